// Round 5
// baseline (594.539 us; speedup 1.0000x reference)
//
#include <hip/hip_runtime.h>
#include <math.h>

#define K_PATCHES 25
#define GRID_SIDE 20
#define G_PTS     400
#define LATENT    1024
#define BATCH     16

typedef _Float16 f16x8 __attribute__((ext_vector_type(8)));
typedef _Float16 f16x4 __attribute__((ext_vector_type(4)));
typedef float    f32x4 __attribute__((ext_vector_type(4)));

// ws layout (bytes)
#define BASE_OFF 0                      // 16*25*1024 f32 = 1,638,400
#define WT2_OFF  1638400                // 25*512*1024 f16 = 26,214,400
#define WT3_OFF  27852800               // 25*256*512 f16  =  6,553,600
#define WT4_OFF  34406400               // 25*128*256 f16  =  1,638,400

// ---------------------------------------------------------------------------
// Kernel 1: base[b][p][o] = b1[p][o] + sum_k x[b][k]*W1[p][k][o]  (o<1024)
// ---------------------------------------------------------------------------
__global__ __launch_bounds__(128)
void base_kernel(const float* __restrict__ x,
                 const float* __restrict__ W1,
                 const float* __restrict__ b1,
                 float* __restrict__ base) {
    __shared__ float xs[BATCH][LATENT];   // 64 KB
    const int p  = blockIdx.x >> 3;
    const int oc = blockIdx.x & 7;
    const int o  = oc * 128 + threadIdx.x;

    for (int idx = threadIdx.x; idx < BATCH * LATENT / 4; idx += 128)
        ((float4*)xs)[idx] = ((const float4*)x)[idx];
    __syncthreads();

    float acc[BATCH];
#pragma unroll
    for (int b = 0; b < BATCH; ++b) acc[b] = 0.0f;

    const float* Wp = W1 + (size_t)p * 1026 * 1024 + o;
    for (int k = 0; k < LATENT; k += 4) {
        const float w0 = Wp[(size_t)(k + 0) * 1024];
        const float w1 = Wp[(size_t)(k + 1) * 1024];
        const float w2 = Wp[(size_t)(k + 2) * 1024];
        const float w3 = Wp[(size_t)(k + 3) * 1024];
#pragma unroll
        for (int b = 0; b < BATCH; ++b) {
            const float4 xv = *(const float4*)&xs[b][k];
            acc[b] = fmaf(xv.w, w3, fmaf(xv.z, w2, fmaf(xv.y, w1, fmaf(xv.x, w0, acc[b]))));
        }
    }

    const float bias = b1[p * 1024 + o];
    for (int b = 0; b < BATCH; ++b)
        base[(size_t)(b * K_PATCHES + p) * 1024 + o] = acc[b] + bias;
}

// ---------------------------------------------------------------------------
// Transpose + fp16 convert: W[p][K][N] f32 -> Wt[p][N][K] f16.
// ---------------------------------------------------------------------------
__global__ __launch_bounds__(256)
void conv_tr_kernel(const float* __restrict__ W, _Float16* __restrict__ Wt,
                    int K, int N) {
    __shared__ float tile[64][65];
    const int tpp = (K / 64) * (N / 64);
    const int p   = blockIdx.x / tpp;
    const int rem = blockIdx.x % tpp;
    const int kt  = rem / (N / 64);
    const int nt  = rem % (N / 64);
    const int tr  = threadIdx.x >> 6;
    const int tc  = threadIdx.x & 63;

    const float* Wp = W + ((size_t)p * K + kt * 64) * N + nt * 64;
#pragma unroll
    for (int i = 0; i < 64; i += 4)
        tile[i + tr][tc] = Wp[(size_t)(i + tr) * N + tc];
    __syncthreads();

    _Float16* Wtp = Wt + ((size_t)p * N + nt * 64) * K + kt * 64;
#pragma unroll
    for (int i = 0; i < 64; i += 4)
        Wtp[(size_t)(i + tr) * K + tc] = (_Float16)tile[tc][i + tr];
}

// ---------------------------------------------------------------------------
// Fused MFMA kernel:
//  - B fragments read DIRECTLY global->reg (L2-resident; waves own disjoint
//    N-slices so LDS staging of B shared nothing), 1-chunk register prefetch.
//  - Activations in LDS with canonical conflict-free layout [ko][row][8 f16]:
//    lane(lq,l16) reads ((ko*64)+row)*16 -> 16 consecutive lanes hit 16
//    contiguous 16B chunks (linear pattern, zero bank conflicts).
//  - h1 double-buffered, 1 barrier/chunk in layer 2; layers 3/4 barrier-free.
// LDS: 136 KB.
// ---------------------------------------------------------------------------
__global__ __launch_bounds__(512)
void fused_mfma(const float* __restrict__ base,
                const float* __restrict__ W1,
                const _Float16* __restrict__ Wt2, const float* __restrict__ b2,
                const _Float16* __restrict__ Wt3, const float* __restrict__ b3,
                const _Float16* __restrict__ Wt4, const float* __restrict__ b4,
                const float* __restrict__ W5, const float* __restrict__ b5,
                float* __restrict__ out) {
    __shared__ __align__(16) unsigned char LDS[139264];
    constexpr int OFF_SB = 0;        // 2 x 4KB  base rows f32
    constexpr int OFF_WU = 8192;     // 4KB
    constexpr int OFF_WV = 12288;    // 4KB
    constexpr int OFF_H1 = 16384;    // 2 x 4KB  [4 ko][64 r][8 f16]
    constexpr int OFF_H2 = 24576;    // 64KB     [64 ko][64 r][8]
    constexpr int OFF_H3 = 90112;    // 32KB     [32 ko][64 r][8]
    constexpr int OFF_H4 = 122880;   // 16KB     [16 ko][64 r][8]

    // bijective XCD swizzle: 2500 blocks -> 8 XCDs, same-patch adjacency
    const int bid = blockIdx.x;
    const int xcd = bid & 7;
    const int ii  = bid >> 3;
    const int ord = (xcd < 4) ? xcd * 313 + ii : 4 * 313 + (xcd - 4) * 312 + ii;
    const int p     = ord / 100;
    const int rbase = (ord % 100) * 64;

    const int t    = threadIdx.x;
    const int lane = t & 63;
    const int w    = t >> 6;      // 0..7 : wave owns N-slice
    const int l16  = lane & 15;
    const int lq   = lane >> 4;   // 0..3 : k-octet

    float* sb0  = (float*)(LDS + OFF_SB);
    float* sb1  = sb0 + 1024;
    float* swuf = (float*)(LDS + OFF_WU);
    float* swvf = (float*)(LDS + OFF_WV);

    const int b0  = rbase / 400;
    const int b1i = (rbase + 63) / 400;
    {
        const float* base0 = base + (size_t)(b0 * K_PATCHES + p) * 1024;
        const float* base1 = base + (size_t)(b1i * K_PATCHES + p) * 1024;
        const float* wup   = W1 + (size_t)p * 1026 * 1024 + (size_t)1024 * 1024;
        if (t < 256) ((float4*)sb0)[t] = ((const float4*)base0)[t];
        else         ((float4*)sb1)[t - 256] = ((const float4*)base1)[t - 256];
        if (t < 256) ((float4*)swuf)[t] = ((const float4*)wup)[t];
        else         ((float4*)swvf)[t - 256] = ((const float4*)(wup + 1024))[t - 256];
    }
    __syncthreads();

    // ---- h1 producer constants: thread t -> (pko, pr, phalf): 4 f16 each
    const int pko   = t >> 7;          // 0..3
    const int pr    = (t >> 1) & 63;   // row 0..63
    const int phalf = t & 1;           // low/high 4 of the octet
    const float* sbm2 = (rbase + pr < (b0 + 1) * 400) ? sb0 : sb1;
    const int pg  = (rbase + pr) % 400;
    const float pu = (float)(pg % GRID_SIDE) * (1.0f / 19.0f);
    const float pv = (float)(pg / GRID_SIDE) * (1.0f / 19.0f);
    const unsigned pwoff = (unsigned)((pko * 64 + pr) * 16 + phalf * 8);

    auto produce2 = [&](int kc, unsigned char* dst) {
        const int k = kc + pko * 8 + phalf * 4;
        const float4 bv = *(const float4*)&sbm2[k];
        const float4 uu = *(const float4*)&swuf[k];
        const float4 vv = *(const float4*)&swvf[k];
        f16x4 hv;
        hv[0] = (_Float16)fmaxf(fmaf(pv, vv.x, fmaf(pu, uu.x, bv.x)), 0.0f);
        hv[1] = (_Float16)fmaxf(fmaf(pv, vv.y, fmaf(pu, uu.y, bv.y)), 0.0f);
        hv[2] = (_Float16)fmaxf(fmaf(pv, vv.z, fmaf(pu, uu.z, bv.z)), 0.0f);
        hv[3] = (_Float16)fmaxf(fmaf(pv, vv.w, fmaf(pu, uu.w, bv.w)), 0.0f);
        *(f16x4*)(dst + pwoff) = hv;
    };

    // =======================  Layer 2: 64x512, K=1024  ======================
    const _Float16* Wt2p = Wt2 + (size_t)p * 512 * 1024;
    const _Float16* b2base = Wt2p + (size_t)(w * 64 + l16) * 1024 + lq * 8;
    f32x4 acc2[4][4];
    {
        const float* b2p = b2 + p * 512;
#pragma unroll
        for (int nf = 0; nf < 4; ++nf) {
            const float bias = b2p[w * 64 + nf * 16 + l16];
            f32x4 bv = {bias, bias, bias, bias};
#pragma unroll
            for (int mf = 0; mf < 4; ++mf) acc2[mf][nf] = bv;
        }
    }

    f16x8 bA[4], bB[4];
    produce2(0, LDS + OFF_H1);
#pragma unroll
    for (int nf = 0; nf < 4; ++nf)
        bA[nf] = *(const f16x8*)(b2base + (size_t)nf * 16384);
    __syncthreads();

    auto l2step = [&](int c, f16x8 (&bc)[4], f16x8 (&bn)[4]) {
        const unsigned char* h1b = LDS + OFF_H1 + (c & 1) * 4096;
        if (c < 31) {
            const int kc1 = (c + 1) * 32;
#pragma unroll
            for (int nf = 0; nf < 4; ++nf)
                bn[nf] = *(const f16x8*)(b2base + (size_t)nf * 16384 + kc1);
            produce2(kc1, LDS + OFF_H1 + ((c + 1) & 1) * 4096);
        }
        f16x8 a[4];
#pragma unroll
        for (int mf = 0; mf < 4; ++mf)
            a[mf] = *(const f16x8*)(h1b + (lq * 64 + mf * 16 + l16) * 16);
        __builtin_amdgcn_s_setprio(1);
#pragma unroll
        for (int mf = 0; mf < 4; ++mf)
#pragma unroll
            for (int nf = 0; nf < 4; ++nf)
                acc2[mf][nf] = __builtin_amdgcn_mfma_f32_16x16x32_f16(a[mf], bc[nf], acc2[mf][nf], 0, 0, 0);
        __builtin_amdgcn_s_setprio(0);
        __syncthreads();
    };

#pragma unroll 1
    for (int c = 0; c < 32; c += 2) {
        l2step(c,     bA, bB);
        l2step(c + 1, bB, bA);
    }

    // store h2 = relu(acc2) in [64 ko][64 r][8] layout (one-time scalar stores)
#pragma unroll
    for (int mf = 0; mf < 4; ++mf)
#pragma unroll
        for (int nf = 0; nf < 4; ++nf)
#pragma unroll
            for (int r = 0; r < 4; ++r) {
                const int row = mf * 16 + lq * 4 + r;
                const int col = w * 64 + nf * 16 + l16;
                const float v = fmaxf(acc2[mf][nf][r], 0.0f);
                *(_Float16*)(LDS + OFF_H2 + ((col >> 3) * 64 + row) * 16 + (col & 7) * 2) = (_Float16)v;
            }
    __syncthreads();

    // =======================  Layer 3: 64x256, K=512  =======================
    const _Float16* Wt3p = Wt3 + (size_t)p * 256 * 512;
    const _Float16* b3base = Wt3p + (size_t)(w * 32 + l16) * 512 + lq * 8;
    f32x4 acc3[4][2];
    {
        const float* b3p = b3 + p * 256;
#pragma unroll
        for (int nf = 0; nf < 2; ++nf) {
            const float bias = b3p[w * 32 + nf * 16 + l16];
            f32x4 bv = {bias, bias, bias, bias};
#pragma unroll
            for (int mf = 0; mf < 4; ++mf) acc3[mf][nf] = bv;
        }
    }
    f16x8 cA[2], cB[2];
#pragma unroll
    for (int nf = 0; nf < 2; ++nf)
        cA[nf] = *(const f16x8*)(b3base + (size_t)nf * 8192);

    auto l3step = [&](int c, f16x8 (&bc)[2], f16x8 (&bn)[2]) {
        if (c < 15) {
            const int kc1 = (c + 1) * 32;
#pragma unroll
            for (int nf = 0; nf < 2; ++nf)
                bn[nf] = *(const f16x8*)(b3base + (size_t)nf * 8192 + kc1);
        }
        f16x8 a[4];
#pragma unroll
        for (int mf = 0; mf < 4; ++mf)
            a[mf] = *(const f16x8*)(LDS + OFF_H2 + ((c * 4 + lq) * 64 + mf * 16 + l16) * 16);
        __builtin_amdgcn_s_setprio(1);
#pragma unroll
        for (int mf = 0; mf < 4; ++mf)
#pragma unroll
            for (int nf = 0; nf < 2; ++nf)
                acc3[mf][nf] = __builtin_amdgcn_mfma_f32_16x16x32_f16(a[mf], bc[nf], acc3[mf][nf], 0, 0, 0);
        __builtin_amdgcn_s_setprio(0);
    };

#pragma unroll 1
    for (int c = 0; c < 16; c += 2) {
        l3step(c,     cA, cB);
        l3step(c + 1, cB, cA);
    }

    // store h3 in [32 ko][64 r][8]
#pragma unroll
    for (int mf = 0; mf < 4; ++mf)
#pragma unroll
        for (int nf = 0; nf < 2; ++nf)
#pragma unroll
            for (int r = 0; r < 4; ++r) {
                const int row = mf * 16 + lq * 4 + r;
                const int col = w * 32 + nf * 16 + l16;
                const float v = fmaxf(acc3[mf][nf][r], 0.0f);
                *(_Float16*)(LDS + OFF_H3 + ((col >> 3) * 64 + row) * 16 + (col & 7) * 2) = (_Float16)v;
            }
    __syncthreads();

    // =======================  Layer 4: 64x128, K=256  =======================
    const _Float16* Wt4p = Wt4 + (size_t)p * 128 * 256;
    const _Float16* b4base = Wt4p + (size_t)(w * 16 + l16) * 256 + lq * 8;
    f32x4 acc4[4];
    {
        const float* b4p = b4 + p * 128;
        const float bias = b4p[w * 16 + l16];
        f32x4 bv = {bias, bias, bias, bias};
#pragma unroll
        for (int mf = 0; mf < 4; ++mf) acc4[mf] = bv;
    }
    f16x8 dA, dB;
    dA = *(const f16x8*)(b4base);

    auto l4step = [&](int c, f16x8& bc, f16x8& bn) {
        if (c < 7)
            bn = *(const f16x8*)(b4base + (c + 1) * 32);
        f16x8 a[4];
#pragma unroll
        for (int mf = 0; mf < 4; ++mf)
            a[mf] = *(const f16x8*)(LDS + OFF_H3 + ((c * 4 + lq) * 64 + mf * 16 + l16) * 16);
        __builtin_amdgcn_s_setprio(1);
#pragma unroll
        for (int mf = 0; mf < 4; ++mf)
            acc4[mf] = __builtin_amdgcn_mfma_f32_16x16x32_f16(a[mf], bc, acc4[mf], 0, 0, 0);
        __builtin_amdgcn_s_setprio(0);
    };

#pragma unroll 1
    for (int c = 0; c < 8; c += 2) {
        l4step(c,     dA, dB);
        l4step(c + 1, dB, dA);
    }

    // store h4 in [16 ko][64 r][8]
#pragma unroll
    for (int mf = 0; mf < 4; ++mf)
#pragma unroll
        for (int r = 0; r < 4; ++r) {
            const int row = mf * 16 + lq * 4 + r;
            const int col = w * 16 + l16;
            const float v = fmaxf(acc4[mf][r], 0.0f);
            *(_Float16*)(LDS + OFF_H4 + ((col >> 3) * 64 + row) * 16 + (col & 7) * 2) = (_Float16)v;
        }
    __syncthreads();

    // =======================  Layer 5: 64x3, K=128, tanh  ===================
    if (t < 192) {
        const int m = t / 3;
        const int c = t % 3;
        const float* W5p = W5 + p * 128 * 3;
        float acc = b5[p * 3 + c];
#pragma unroll 4
        for (int k = 0; k < 128; ++k) {
            const _Float16 hv = *(const _Float16*)(LDS + OFF_H4 + ((k >> 3) * 64 + m) * 16 + (k & 7) * 2);
            acc = fmaf((float)hv, W5p[k * 3 + c], acc);
        }
        const int r  = rbase + m;
        const int bb = r / 400;
        const int gg = r % 400;
        out[((size_t)(bb * K_PATCHES + p) * G_PTS + gg) * 3 + c] = tanhf(acc);
    }
}

extern "C" void kernel_launch(void* const* d_in, const int* in_sizes, int n_in,
                              void* d_out, int out_size, void* d_ws, size_t ws_size,
                              hipStream_t stream) {
    const float* x  = (const float*)d_in[0];
    const float* W1 = (const float*)d_in[1];
    const float* b1 = (const float*)d_in[2];
    const float* W2 = (const float*)d_in[3];
    const float* b2 = (const float*)d_in[4];
    const float* W3 = (const float*)d_in[5];
    const float* b3 = (const float*)d_in[6];
    const float* W4 = (const float*)d_in[7];
    const float* b4 = (const float*)d_in[8];
    const float* W5 = (const float*)d_in[9];
    const float* b5 = (const float*)d_in[10];
    float* out = (float*)d_out;

    float*     base = (float*)((char*)d_ws + BASE_OFF);
    _Float16*  Wt2  = (_Float16*)((char*)d_ws + WT2_OFF);
    _Float16*  Wt3  = (_Float16*)((char*)d_ws + WT3_OFF);
    _Float16*  Wt4  = (_Float16*)((char*)d_ws + WT4_OFF);

    base_kernel<<<K_PATCHES * 8, 128, 0, stream>>>(x, W1, b1, base);

    conv_tr_kernel<<<K_PATCHES * (1024 / 64) * (512 / 64), 256, 0, stream>>>(W2, Wt2, 1024, 512);
    conv_tr_kernel<<<K_PATCHES * (512 / 64) * (256 / 64),  256, 0, stream>>>(W3, Wt3, 512, 256);
    conv_tr_kernel<<<K_PATCHES * (256 / 64) * (128 / 64),  256, 0, stream>>>(W4, Wt4, 256, 128);

    fused_mfma<<<K_PATCHES * 100, 512, 0, stream>>>(
        base, W1, Wt2, b2, Wt3, b3, Wt4, b4, W5, b5, out);
}